// Round 1
// baseline (625.974 us; speedup 1.0000x reference)
//
#include <hip/hip_runtime.h>

#define THREADS 256

typedef unsigned short u16;
typedef __attribute__((ext_vector_type(8))) short bf16x8;
typedef __attribute__((ext_vector_type(4))) float f32x4;

// ---- helpers ----------------------------------------------------------
__device__ __forceinline__ u16 f2bf(float f) {
  unsigned int u = __float_as_uint(f);
  u += 0x7fffu + ((u >> 16) & 1u);   // RNE
  return (u16)(u >> 16);
}
__device__ __forceinline__ float bf2f(u16 s) {
  return __uint_as_float(((unsigned int)s) << 16);
}
__device__ __forceinline__ bf16x8 ld8g(const u16* p) {
  return *reinterpret_cast<const bf16x8*>(p);
}
__device__ __forceinline__ bf16x8 ld8s(const u16* p) {
  return *reinterpret_cast<const bf16x8*>(p);
}
__device__ __forceinline__ void st4bf(u16* dst, float4 v) {
  unsigned int lo = (unsigned int)f2bf(v.x) | ((unsigned int)f2bf(v.y) << 16);
  unsigned int hi = (unsigned int)f2bf(v.z) | ((unsigned int)f2bf(v.w) << 16);
  uint2 u; u.x = lo; u.y = hi;
  *reinterpret_cast<uint2*>(dst) = u;
}

// ---- phase 0: cast fp32 -> bf16 (+ aV transpose to (i,d,j)) -----------
// float4 segments: x 2097152 | Wq 65536 | Wk 65536 | Wv 65536 | aK 1048576 | aV 1048576
__global__ __launch_bounds__(THREADS) void cast_all(
    const float* __restrict__ x, const float* __restrict__ wq,
    const float* __restrict__ wk, const float* __restrict__ wv,
    const float* __restrict__ aK, const float* __restrict__ aV,
    u16* __restrict__ xb, u16* __restrict__ wqb, u16* __restrict__ wkb,
    u16* __restrict__ wvb, u16* __restrict__ aKb, u16* __restrict__ aVtb) {
  int t = blockIdx.x * THREADS + threadIdx.x;  // float4 index
  if (t < 2097152) {
    float4 v = reinterpret_cast<const float4*>(x)[t];
    st4bf(xb + t * 4, v);
  } else if (t < 2162688) {
    int q = t - 2097152;
    float4 v = reinterpret_cast<const float4*>(wq)[q];
    st4bf(wqb + q * 4, v);
  } else if (t < 2228224) {
    int q = t - 2162688;
    float4 v = reinterpret_cast<const float4*>(wk)[q];
    st4bf(wkb + q * 4, v);
  } else if (t < 2293760) {
    int q = t - 2228224;
    float4 v = reinterpret_cast<const float4*>(wv)[q];
    st4bf(wvb + q * 4, v);
  } else if (t < 3342336) {
    int q = t - 2293760;
    float4 v = reinterpret_cast<const float4*>(aK)[q];
    st4bf(aKb + q * 4, v);
  } else if (t < 4390912) {
    int q = t - 3342336;
    float4 v = reinterpret_cast<const float4*>(aV)[q];
    int base = q * 4;
    int i = base >> 14;          // /(256*64)
    int rem = base & 16383;
    int j = rem >> 6;
    int d = rem & 63;
    // aVt[i][d][j]
    aVtb[(i * 64 + d + 0) * 256 + j] = f2bf(v.x);
    aVtb[(i * 64 + d + 1) * 256 + j] = f2bf(v.y);
    aVtb[(i * 64 + d + 2) * 256 + j] = f2bf(v.z);
    aVtb[(i * 64 + d + 3) * 256 + j] = f2bf(v.w);
  }
}

// ---- phase 1: projection Y = Xb @ Wb^T, permuted epilogue -------------
// mode 0: Q -> (i, hm, d)   mode 1: K/V -> (hm, j, d)
__global__ __launch_bounds__(THREADS) void proj_k(
    const u16* __restrict__ xb, const u16* __restrict__ wb,
    u16* __restrict__ dst, int mode) {
  const int bi = blockIdx.x;
  const int bm = bi >> 3, bn = bi & 7;
  const int tid = threadIdx.x;
  const int wave = tid >> 6, lane = tid & 63;
  const int quad = lane >> 4, l15 = lane & 15;
  f32x4 acc[4];
#pragma unroll
  for (int nt = 0; nt < 4; ++nt) acc[nt] = (f32x4){0.f, 0.f, 0.f, 0.f};
  const u16* arow = xb + (bm * 64 + wave * 16 + l15) * 512 + quad * 8;
  for (int k0 = 0; k0 < 16; ++k0) {
    bf16x8 a = ld8g(arow + k0 * 32);
#pragma unroll
    for (int nt = 0; nt < 4; ++nt) {
      bf16x8 b = ld8g(wb + (bn * 64 + nt * 16 + l15) * 512 + k0 * 32 + quad * 8);
      acc[nt] = __builtin_amdgcn_mfma_f32_16x16x32_bf16(a, b, acc[nt], 0, 0, 0);
    }
  }
#pragma unroll
  for (int nt = 0; nt < 4; ++nt) {
#pragma unroll
    for (int r = 0; r < 4; ++r) {
      int row = bm * 64 + wave * 16 + quad * 4 + r;  // ml index
      int m = row >> 8, l = row & 255;
      int col = bn * 64 + nt * 16 + l15;             // e index
      int h = col >> 6, dh = col & 63;
      float v = acc[nt][r];
      if (mode == 0)
        dst[(l * 512 + h * 64 + m) * 64 + dh] = f2bf(v);   // (i, hm, d)
      else
        dst[((h * 64 + m) * 256 + l) * 64 + dh] = f2bf(v); // (hm, j, d)
    }
  }
}

// ---- phase 2: e2[hm][i][j] = sum_d q[i][hm][d] * aK[i][j][d] ----------
// grid 2048: i = bi>>3, hmt = bi&7 (64 hm rows per block), N=256, K=64
__global__ __launch_bounds__(THREADS) void e2_k(
    const u16* __restrict__ qb, const u16* __restrict__ aKb,
    u16* __restrict__ e2g) {
  const int bi = blockIdx.x;
  const int i = bi >> 3, hmt = bi & 7;
  const int tid = threadIdx.x;
  const int wave = tid >> 6, lane = tid & 63;
  const int quad = lane >> 4, l15 = lane & 15;
  f32x4 acc[16];
#pragma unroll
  for (int nt = 0; nt < 16; ++nt) acc[nt] = (f32x4){0.f, 0.f, 0.f, 0.f};
  bf16x8 a[2];
#pragma unroll
  for (int ks = 0; ks < 2; ++ks)
    a[ks] = ld8g(qb + (i * 512 + hmt * 64 + wave * 16 + l15) * 64 + ks * 32 + quad * 8);
#pragma unroll
  for (int nt = 0; nt < 16; ++nt) {
#pragma unroll
    for (int ks = 0; ks < 2; ++ks) {
      bf16x8 b = ld8g(aKb + (i * 256 + nt * 16 + l15) * 64 + ks * 32 + quad * 8);
      acc[nt] = __builtin_amdgcn_mfma_f32_16x16x32_bf16(a[ks], b, acc[nt], 0, 0, 0);
    }
  }
#pragma unroll
  for (int nt = 0; nt < 16; ++nt) {
#pragma unroll
    for (int r = 0; r < 4; ++r) {
      int hm = hmt * 64 + wave * 16 + quad * 4 + r;
      int j = nt * 16 + l15;
      e2g[(hm * 256 + i) * 256 + j] = f2bf(acc[nt][r]);
    }
  }
}

// ---- phase 3a: S = (QK^T + e2)/8, softmax over j, alpha overwrites e2 -
// grid 512 (hm); i-tiles of 64 inside. No LDS.
__global__ __launch_bounds__(THREADS) void scores_k(
    const u16* __restrict__ qb, const u16* __restrict__ kb,
    u16* __restrict__ e2g /* in: e2, out: alpha */) {
  const int hm = blockIdx.x;
  const int tid = threadIdx.x;
  const int wave = tid >> 6, lane = tid & 63;
  const int quad = lane >> 4, l15 = lane & 15;
  for (int it = 0; it < 4; ++it) {
    f32x4 acc[16];
#pragma unroll
    for (int nt = 0; nt < 16; ++nt) acc[nt] = (f32x4){0.f, 0.f, 0.f, 0.f};
    bf16x8 a[2];
#pragma unroll
    for (int ks = 0; ks < 2; ++ks)
      a[ks] = ld8g(qb + ((it * 64 + wave * 16 + l15) * 512 + hm) * 64 + ks * 32 + quad * 8);
#pragma unroll
    for (int nt = 0; nt < 16; ++nt) {
#pragma unroll
      for (int ks = 0; ks < 2; ++ks) {
        bf16x8 b = ld8g(kb + (hm * 256 + nt * 16 + l15) * 64 + ks * 32 + quad * 8);
        acc[nt] = __builtin_amdgcn_mfma_f32_16x16x32_bf16(a[ks], b, acc[nt], 0, 0, 0);
      }
    }
    // add e2, scale
#pragma unroll
    for (int nt = 0; nt < 16; ++nt) {
#pragma unroll
      for (int r = 0; r < 4; ++r) {
        int i = it * 64 + wave * 16 + quad * 4 + r;
        int j = nt * 16 + l15;
        float e2v = bf2f(e2g[(hm * 256 + i) * 256 + j]);
        acc[nt][r] = (acc[nt][r] + e2v) * 0.125f;
      }
    }
    // rowwise softmax: row lives across 16 lanes of same quad x 16 nt
#pragma unroll
    for (int r = 0; r < 4; ++r) {
      float mx = -3.0e38f;
#pragma unroll
      for (int nt = 0; nt < 16; ++nt) mx = fmaxf(mx, acc[nt][r]);
      for (int msk = 1; msk < 16; msk <<= 1) mx = fmaxf(mx, __shfl_xor(mx, msk));
      float s = 0.f;
#pragma unroll
      for (int nt = 0; nt < 16; ++nt) {
        float p = expf(acc[nt][r] - mx);
        acc[nt][r] = p;
        s += p;
      }
      for (int msk = 1; msk < 16; msk <<= 1) s += __shfl_xor(s, msk);
      float inv = 1.0f / s;
      int i = it * 64 + wave * 16 + quad * 4 + r;
#pragma unroll
      for (int nt = 0; nt < 16; ++nt) {
        int j = nt * 16 + l15;
        e2g[(hm * 256 + i) * 256 + j] = f2bf(acc[nt][r] * inv);
      }
    }
  }
}

// ---- phase 3b: z1 = alpha @ V, atomic m-sum into out ------------------
// grid 512 (hm). LDS: V^T (64 d x 256 j, stride 264)
__global__ __launch_bounds__(THREADS) void z1_k(
    const u16* __restrict__ alphag, const u16* __restrict__ vb,
    float* __restrict__ out) {
  const int hm = blockIdx.x;
  const int h = hm >> 6;
  const int tid = threadIdx.x;
  const int wave = tid >> 6, lane = tid & 63;
  const int quad = lane >> 4, l15 = lane & 15;
  __shared__ u16 Vt[64 * 264];
#pragma unroll
  for (int c = 0; c < 8; ++c) {
    int lin = c * 2048 + tid * 8;
    int j = lin >> 6, d0 = lin & 63;
    uint4 raw = *reinterpret_cast<const uint4*>(vb + hm * 16384 + lin);
    u16 tmp[8];
    *reinterpret_cast<uint4*>(tmp) = raw;
#pragma unroll
    for (int u = 0; u < 8; ++u) Vt[(d0 + u) * 264 + j] = tmp[u];
  }
  __syncthreads();
  for (int it = 0; it < 4; ++it) {
    f32x4 acc[4];
#pragma unroll
    for (int nt = 0; nt < 4; ++nt) acc[nt] = (f32x4){0.f, 0.f, 0.f, 0.f};
#pragma unroll
    for (int ks = 0; ks < 8; ++ks) {
      bf16x8 a = ld8g(alphag + (hm * 256 + it * 64 + wave * 16 + l15) * 256 + ks * 32 + quad * 8);
#pragma unroll
      for (int nt = 0; nt < 4; ++nt) {
        bf16x8 b = ld8s(&Vt[(nt * 16 + l15) * 264 + ks * 32 + quad * 8]);
        acc[nt] = __builtin_amdgcn_mfma_f32_16x16x32_bf16(a, b, acc[nt], 0, 0, 0);
      }
    }
#pragma unroll
    for (int nt = 0; nt < 4; ++nt) {
#pragma unroll
      for (int r = 0; r < 4; ++r) {
        int i = it * 64 + wave * 16 + quad * 4 + r;
        int e = h * 64 + nt * 16 + l15;
        atomicAdd(&out[i * 512 + e], acc[nt][r]);
      }
    }
  }
}

// ---- phase 4: z2 = alpha @ aV[i], atomic m-sum into out ---------------
// grid 2048: i = bi>>3, hmt = bi&7. M=64 hm, N=64 d, K=256 j. No LDS.
__global__ __launch_bounds__(THREADS) void z2_k(
    const u16* __restrict__ alphag, const u16* __restrict__ aVtb,
    float* __restrict__ out) {
  const int bi = blockIdx.x;
  const int i = bi >> 3, hmt = bi & 7;
  const int tid = threadIdx.x;
  const int wave = tid >> 6, lane = tid & 63;
  const int quad = lane >> 4, l15 = lane & 15;
  f32x4 acc[4];
#pragma unroll
  for (int nt = 0; nt < 4; ++nt) acc[nt] = (f32x4){0.f, 0.f, 0.f, 0.f};
#pragma unroll
  for (int ks = 0; ks < 8; ++ks) {
    bf16x8 a = ld8g(alphag + ((hmt * 64 + wave * 16 + l15) * 256 + i) * 256 + ks * 32 + quad * 8);
#pragma unroll
    for (int nt = 0; nt < 4; ++nt) {
      bf16x8 b = ld8g(aVtb + (i * 64 + nt * 16 + l15) * 256 + ks * 32 + quad * 8);
      acc[nt] = __builtin_amdgcn_mfma_f32_16x16x32_bf16(a, b, acc[nt], 0, 0, 0);
    }
  }
#pragma unroll
  for (int nt = 0; nt < 4; ++nt) {
#pragma unroll
    for (int r = 0; r < 4; ++r) {
      int hm = hmt * 64 + wave * 16 + quad * 4 + r;
      int h = hm >> 6;
      int d = nt * 16 + l15;
      atomicAdd(&out[i * 512 + h * 64 + d], acc[nt][r]);
    }
  }
}

// ---- launch -----------------------------------------------------------
extern "C" void kernel_launch(void* const* d_in, const int* in_sizes, int n_in,
                              void* d_out, int out_size, void* d_ws, size_t ws_size,
                              hipStream_t stream) {
  const float* x  = (const float*)d_in[0];
  const float* wq = (const float*)d_in[1];
  const float* wk = (const float*)d_in[2];
  const float* wv = (const float*)d_in[3];
  const float* aK = (const float*)d_in[4];
  const float* aV = (const float*)d_in[5];
  float* out = (float*)d_out;

  char* ws = (char*)d_ws;
  u16* xb   = (u16*)(ws + 0);          // 16777216 B
  u16* wqb  = (u16*)(ws + 16777216);   //   524288
  u16* wkb  = (u16*)(ws + 17301504);   //   524288
  u16* wvb  = (u16*)(ws + 17825792);   //   524288
  u16* aKb  = (u16*)(ws + 18350080);   //  8388608
  u16* aVtb = (u16*)(ws + 26738688);   //  8388608
  u16* qb   = (u16*)(ws + 35127296);   // 16777216  (i, hm, d)
  u16* kb   = (u16*)(ws + 51904512);   // 16777216  (hm, j, d)
  u16* vb   = (u16*)(ws + 68681728);   // 16777216  (hm, j, d)
  u16* e2g  = (u16*)(ws + 85458944);   // 67108864  e2 then alpha (hm, i, j)
  // total 152567808 B

  hipMemsetAsync(d_out, 0, 256 * 512 * sizeof(float), stream);

  cast_all<<<17152, THREADS, 0, stream>>>(x, wq, wk, wv, aK, aV,
                                          xb, wqb, wkb, wvb, aKb, aVtb);
  proj_k<<<2048, THREADS, 0, stream>>>(xb, wqb, qb, 0);
  proj_k<<<2048, THREADS, 0, stream>>>(xb, wkb, kb, 1);
  proj_k<<<2048, THREADS, 0, stream>>>(xb, wvb, vb, 1);
  e2_k<<<2048, THREADS, 0, stream>>>(qb, aKb, e2g);
  scores_k<<<512, THREADS, 0, stream>>>(qb, kb, e2g);
  z1_k<<<512, THREADS, 0, stream>>>(e2g, vb, out);
  z2_k<<<2048, THREADS, 0, stream>>>(e2g, aVtb, out);
}

// Round 2
// 525.450 us; speedup vs baseline: 1.1913x; 1.1913x over previous
//
#include <hip/hip_runtime.h>

#define THREADS 256

typedef unsigned short u16;
typedef __attribute__((ext_vector_type(8))) short bf16x8;
typedef __attribute__((ext_vector_type(4))) float f32x4;

// ---- helpers ----------------------------------------------------------
__device__ __forceinline__ u16 f2bf(float f) {
  unsigned int u = __float_as_uint(f);
  u += 0x7fffu + ((u >> 16) & 1u);   // RNE
  return (u16)(u >> 16);
}
__device__ __forceinline__ float bf2f(u16 s) {
  return __uint_as_float(((unsigned int)s) << 16);
}
__device__ __forceinline__ bf16x8 ld8g(const u16* p) {
  return *reinterpret_cast<const bf16x8*>(p);
}
__device__ __forceinline__ bf16x8 ld8s(const u16* p) {
  return *reinterpret_cast<const bf16x8*>(p);
}
__device__ __forceinline__ void st4bf(u16* dst, float4 v) {
  unsigned int lo = (unsigned int)f2bf(v.x) | ((unsigned int)f2bf(v.y) << 16);
  unsigned int hi = (unsigned int)f2bf(v.z) | ((unsigned int)f2bf(v.w) << 16);
  uint2 u; u.x = lo; u.y = hi;
  *reinterpret_cast<uint2*>(dst) = u;
}

// ---- phase 0: cast fp32 -> bf16 (+ aV transpose to (i,d,j)) -----------
__global__ __launch_bounds__(THREADS) void cast_all(
    const float* __restrict__ x, const float* __restrict__ wq,
    const float* __restrict__ wk, const float* __restrict__ wv,
    const float* __restrict__ aK, const float* __restrict__ aV,
    u16* __restrict__ xb, u16* __restrict__ wqb, u16* __restrict__ wkb,
    u16* __restrict__ wvb, u16* __restrict__ aKb, u16* __restrict__ aVtb) {
  int t = blockIdx.x * THREADS + threadIdx.x;  // float4 index
  if (t < 2097152) {
    float4 v = reinterpret_cast<const float4*>(x)[t];
    st4bf(xb + t * 4, v);
  } else if (t < 2162688) {
    int q = t - 2097152;
    float4 v = reinterpret_cast<const float4*>(wq)[q];
    st4bf(wqb + q * 4, v);
  } else if (t < 2228224) {
    int q = t - 2162688;
    float4 v = reinterpret_cast<const float4*>(wk)[q];
    st4bf(wkb + q * 4, v);
  } else if (t < 2293760) {
    int q = t - 2228224;
    float4 v = reinterpret_cast<const float4*>(wv)[q];
    st4bf(wvb + q * 4, v);
  } else if (t < 3342336) {
    int q = t - 2293760;
    float4 v = reinterpret_cast<const float4*>(aK)[q];
    st4bf(aKb + q * 4, v);
  } else if (t < 4390912) {
    int q = t - 3342336;
    float4 v = reinterpret_cast<const float4*>(aV)[q];
    int base = q * 4;
    int i = base >> 14;          // /(256*64)
    int rem = base & 16383;
    int j = rem >> 6;
    int d = rem & 63;
    aVtb[(i * 64 + d + 0) * 256 + j] = f2bf(v.x);
    aVtb[(i * 64 + d + 1) * 256 + j] = f2bf(v.y);
    aVtb[(i * 64 + d + 2) * 256 + j] = f2bf(v.z);
    aVtb[(i * 64 + d + 3) * 256 + j] = f2bf(v.w);
  }
}

// ---- phase 1: projection Y = Xb @ Wb^T -> (hm, l, dh) -----------------
__global__ __launch_bounds__(THREADS) void proj_k(
    const u16* __restrict__ xb, const u16* __restrict__ wb,
    u16* __restrict__ dst) {
  const int bi = blockIdx.x;
  const int bm = bi >> 3, bn = bi & 7;
  const int tid = threadIdx.x;
  const int wave = tid >> 6, lane = tid & 63;
  const int quad = lane >> 4, l15 = lane & 15;
  f32x4 acc[4];
#pragma unroll
  for (int nt = 0; nt < 4; ++nt) acc[nt] = (f32x4){0.f, 0.f, 0.f, 0.f};
  const u16* arow = xb + (bm * 64 + wave * 16 + l15) * 512 + quad * 8;
  for (int k0 = 0; k0 < 16; ++k0) {
    bf16x8 a = ld8g(arow + k0 * 32);
#pragma unroll
    for (int nt = 0; nt < 4; ++nt) {
      bf16x8 b = ld8g(wb + (bn * 64 + nt * 16 + l15) * 512 + k0 * 32 + quad * 8);
      acc[nt] = __builtin_amdgcn_mfma_f32_16x16x32_bf16(a, b, acc[nt], 0, 0, 0);
    }
  }
#pragma unroll
  for (int nt = 0; nt < 4; ++nt) {
#pragma unroll
    for (int r = 0; r < 4; ++r) {
      int row = bm * 64 + wave * 16 + quad * 4 + r;  // ml index
      int m = row >> 8, l = row & 255;
      int col = bn * 64 + nt * 16 + l15;             // e index
      int h = col >> 6, dh = col & 63;
      dst[((h * 64 + m) * 256 + l) * 64 + dh] = f2bf(acc[nt][r]); // (hm, i/j, d)
    }
  }
}

// ---- phase 2: e2[hm][i][j] = sum_d q[hm][i][d] * aK[i][j][d] ----------
// grid 256 (i); aK[i] staged in LDS; loop over hm tiles of 64.
__global__ __launch_bounds__(THREADS) void e2_k(
    const u16* __restrict__ qh, const u16* __restrict__ aKb,
    u16* __restrict__ e2g) {
  const int i = blockIdx.x;
  const int tid = threadIdx.x;
  const int wave = tid >> 6, lane = tid & 63;
  const int quad = lane >> 4, l15 = lane & 15;
  __shared__ u16 aKl[256 * 72];
#pragma unroll
  for (int c = 0; c < 8; ++c) {
    int lin = (c * 256 + tid) * 8;   // u16 units
    int j = lin >> 6, d0 = lin & 63;
    uint4 raw = *reinterpret_cast<const uint4*>(aKb + i * 16384 + lin);
    *reinterpret_cast<uint4*>(&aKl[j * 72 + d0]) = raw;
  }
  __syncthreads();
  for (int hmt = 0; hmt < 8; ++hmt) {
    f32x4 acc[16];
#pragma unroll
    for (int nt = 0; nt < 16; ++nt) acc[nt] = (f32x4){0.f, 0.f, 0.f, 0.f};
    bf16x8 a[2];
#pragma unroll
    for (int ks = 0; ks < 2; ++ks)
      a[ks] = ld8g(qh + ((hmt * 64 + wave * 16 + l15) * 256 + i) * 64 + ks * 32 + quad * 8);
#pragma unroll
    for (int nt = 0; nt < 16; ++nt) {
#pragma unroll
      for (int ks = 0; ks < 2; ++ks) {
        bf16x8 b = ld8s(&aKl[(nt * 16 + l15) * 72 + ks * 32 + quad * 8]);
        acc[nt] = __builtin_amdgcn_mfma_f32_16x16x32_bf16(a[ks], b, acc[nt], 0, 0, 0);
      }
    }
#pragma unroll
    for (int nt = 0; nt < 16; ++nt) {
#pragma unroll
      for (int r = 0; r < 4; ++r) {
        int hm = hmt * 64 + wave * 16 + quad * 4 + r;
        int j = nt * 16 + l15;
        e2g[(hm * 256 + i) * 256 + j] = f2bf(acc[nt][r]);
      }
    }
  }
}

// ---- phase 3: fused scores+softmax+z1 per hm --------------------------
// S = (QK^T + e2)/8 -> softmax -> alpha (overwrites e2g, for beta_k)
// z1p[hm][i][d] = alpha @ V (bf16 partials, plain stores)
__global__ __launch_bounds__(THREADS) void attn_k(
    const u16* __restrict__ qh, const u16* __restrict__ kb,
    const u16* __restrict__ vb, u16* __restrict__ e2g,
    u16* __restrict__ z1p) {
  const int hm = blockIdx.x;
  const int tid = threadIdx.x;
  const int wave = tid >> 6, lane = tid & 63;
  const int quad = lane >> 4, l15 = lane & 15;
  __shared__ u16 Vt[64 * 264];        // V^T: (d, j) padded
  __shared__ u16 As[4 * 16 * 264];    // per-wave alpha scratch (16 rows x 256 j)
#pragma unroll
  for (int c = 0; c < 8; ++c) {
    int lin = c * 2048 + tid * 8;
    int j = lin >> 6, d0 = lin & 63;
    uint4 raw = *reinterpret_cast<const uint4*>(vb + hm * 16384 + lin);
    u16 tmp[8];
    *reinterpret_cast<uint4*>(tmp) = raw;
#pragma unroll
    for (int u = 0; u < 8; ++u) Vt[(d0 + u) * 264 + j] = tmp[u];
  }
  __syncthreads();
  for (int it = 0; it < 4; ++it) {
    // --- scores: acc init with e2, accumulate e1 ---
    f32x4 acc[16];
#pragma unroll
    for (int nt = 0; nt < 16; ++nt) {
#pragma unroll
      for (int r = 0; r < 4; ++r) {
        int i = it * 64 + wave * 16 + quad * 4 + r;
        int j = nt * 16 + l15;
        acc[nt][r] = bf2f(e2g[(hm * 256 + i) * 256 + j]);
      }
    }
    bf16x8 a[2];
#pragma unroll
    for (int ks = 0; ks < 2; ++ks)
      a[ks] = ld8g(qh + (hm * 256 + it * 64 + wave * 16 + l15) * 64 + ks * 32 + quad * 8);
#pragma unroll
    for (int nt = 0; nt < 16; ++nt) {
#pragma unroll
      for (int ks = 0; ks < 2; ++ks) {
        bf16x8 b = ld8g(kb + (hm * 256 + nt * 16 + l15) * 64 + ks * 32 + quad * 8);
        acc[nt] = __builtin_amdgcn_mfma_f32_16x16x32_bf16(a[ks], b, acc[nt], 0, 0, 0);
      }
    }
    // --- softmax over j (row = 16 lanes x 16 nt) ---
#pragma unroll
    for (int r = 0; r < 4; ++r) {
      float mx = -3.0e38f;
#pragma unroll
      for (int nt = 0; nt < 16; ++nt) mx = fmaxf(mx, acc[nt][r] * 0.125f);
      for (int msk = 1; msk < 16; msk <<= 1) mx = fmaxf(mx, __shfl_xor(mx, msk));
      float s = 0.f;
#pragma unroll
      for (int nt = 0; nt < 16; ++nt) {
        float p = expf(acc[nt][r] * 0.125f - mx);
        acc[nt][r] = p;
        s += p;
      }
      for (int msk = 1; msk < 16; msk <<= 1) s += __shfl_xor(s, msk);
      float inv = 1.0f / s;
      int i = it * 64 + wave * 16 + quad * 4 + r;
      int lrow = quad * 4 + r;   // local row within wave's 16
#pragma unroll
      for (int nt = 0; nt < 16; ++nt) {
        int j = nt * 16 + l15;
        u16 pb = f2bf(acc[nt][r] * inv);
        e2g[(hm * 256 + i) * 256 + j] = pb;              // alpha for beta_k
        As[wave * 4224 + lrow * 264 + j] = pb;           // alpha for z1 A-frags
      }
    }
    __syncthreads();
    // --- z1 tile: alpha(16i x 256j) @ V^T -> (16i x 64d) per wave ---
    f32x4 acc2[4];
#pragma unroll
    for (int nt = 0; nt < 4; ++nt) acc2[nt] = (f32x4){0.f, 0.f, 0.f, 0.f};
#pragma unroll
    for (int ks = 0; ks < 8; ++ks) {
      bf16x8 a2 = ld8s(&As[wave * 4224 + l15 * 264 + ks * 32 + quad * 8]);
#pragma unroll
      for (int nt = 0; nt < 4; ++nt) {
        bf16x8 b2 = ld8s(&Vt[(nt * 16 + l15) * 264 + ks * 32 + quad * 8]);
        acc2[nt] = __builtin_amdgcn_mfma_f32_16x16x32_bf16(a2, b2, acc2[nt], 0, 0, 0);
      }
    }
#pragma unroll
    for (int nt = 0; nt < 4; ++nt) {
#pragma unroll
      for (int r = 0; r < 4; ++r) {
        int i = it * 64 + wave * 16 + quad * 4 + r;
        int d = nt * 16 + l15;
        z1p[hm * 16384 + i * 64 + d] = f2bf(acc2[nt][r]);
      }
    }
    __syncthreads();
  }
}

// ---- phase 4: beta[h][i][j] = sum_m alpha[(h,m)][i][j] ----------------
// grid 2048: h = b>>8, i = b&255. One writer per element, no atomics.
__global__ __launch_bounds__(THREADS) void beta_k(
    const u16* __restrict__ alphag, float* __restrict__ beta) {
  const int b = blockIdx.x;
  const int h = b >> 8, i = b & 255;
  const int j = threadIdx.x;
  float s = 0.f;
  const u16* base = alphag + (size_t)(h * 64) * 65536 + i * 256 + j;
#pragma unroll 4
  for (int m = 0; m < 64; ++m) s += bf2f(base[m * 65536]);
  beta[(h * 256 + i) * 256 + j] = s;
}

// ---- phase 5: z2b[i][h][d] = beta[h][i][:] @ aV[i] --------------------
// grid 256 (i); M=16 (8 valid h), N=64 (4 waves x 16), K=256.
__global__ __launch_bounds__(THREADS) void z2_k(
    const float* __restrict__ beta, const u16* __restrict__ aVtb,
    float* __restrict__ z2b) {
  const int i = blockIdx.x;
  const int tid = threadIdx.x;
  const int wave = tid >> 6, lane = tid & 63;
  const int quad = lane >> 4, l15 = lane & 15;
  f32x4 acc = (f32x4){0.f, 0.f, 0.f, 0.f};
#pragma unroll
  for (int ks = 0; ks < 8; ++ks) {
    u16 ab[8];
    if (l15 < 8) {
      const float* bp = beta + (l15 * 256 + i) * 256 + ks * 32 + quad * 8;
      float4 f0 = *reinterpret_cast<const float4*>(bp);
      float4 f1 = *reinterpret_cast<const float4*>(bp + 4);
      ab[0] = f2bf(f0.x); ab[1] = f2bf(f0.y); ab[2] = f2bf(f0.z); ab[3] = f2bf(f0.w);
      ab[4] = f2bf(f1.x); ab[5] = f2bf(f1.y); ab[6] = f2bf(f1.z); ab[7] = f2bf(f1.w);
    } else {
#pragma unroll
      for (int u = 0; u < 8; ++u) ab[u] = 0;
    }
    bf16x8 a = *reinterpret_cast<bf16x8*>(ab);
    bf16x8 b = ld8g(aVtb + (i * 64 + wave * 16 + l15) * 256 + ks * 32 + quad * 8);
    acc = __builtin_amdgcn_mfma_f32_16x16x32_bf16(a, b, acc, 0, 0, 0);
  }
#pragma unroll
  for (int r = 0; r < 4; ++r) {
    int h = quad * 4 + r;
    if (h < 8) z2b[i * 512 + h * 64 + wave * 16 + l15] = acc[r];
  }
}

// ---- phase 6: out[i][e] = z2b[i][e] + sum_m z1p[(h,m)][i][d] ----------
__global__ __launch_bounds__(THREADS) void reduce_k(
    const u16* __restrict__ z1p, const float* __restrict__ z2b,
    float* __restrict__ out) {
  int o = blockIdx.x * THREADS + threadIdx.x;   // 131072 total
  int i = o >> 9, e = o & 511;
  int h = e >> 6, d = e & 63;
  float s = z2b[o];
  const u16* base = z1p + (size_t)(h * 64) * 16384 + i * 64 + d;
#pragma unroll 4
  for (int m = 0; m < 64; ++m) s += bf2f(base[m * 16384]);
  out[o] = s;
}

// ---- launch -----------------------------------------------------------
extern "C" void kernel_launch(void* const* d_in, const int* in_sizes, int n_in,
                              void* d_out, int out_size, void* d_ws, size_t ws_size,
                              hipStream_t stream) {
  const float* x  = (const float*)d_in[0];
  const float* wq = (const float*)d_in[1];
  const float* wk = (const float*)d_in[2];
  const float* wv = (const float*)d_in[3];
  const float* aK = (const float*)d_in[4];
  const float* aV = (const float*)d_in[5];
  float* out = (float*)d_out;

  char* ws = (char*)d_ws;
  u16* xb    = (u16*)(ws + 0);          // 16 MB: x bf16, later z1p (aliased)
  u16* wqb   = (u16*)(ws + 16777216);
  u16* wkb   = (u16*)(ws + 17301504);
  u16* wvb   = (u16*)(ws + 17825792);
  u16* aKb   = (u16*)(ws + 18350080);   // 8 MB, dead after e2_k -> beta/z2b alias
  float* beta= (float*)(ws + 18350080); // 2 MB  (aliases aKb, used after e2_k)
  float* z2b = (float*)(ws + 20447232); // 0.5 MB
  u16* aVtb  = (u16*)(ws + 26738688);   // 8 MB
  u16* qh    = (u16*)(ws + 35127296);   // 16 MB (hm, i, d)
  u16* kb    = (u16*)(ws + 51904512);   // 16 MB (hm, j, d)
  u16* vb    = (u16*)(ws + 68681728);   // 16 MB (hm, j, d)
  u16* e2g   = (u16*)(ws + 85458944);   // 64 MB: e2 then alpha (hm, i, j)
  u16* z1p   = xb;                      // 16 MB bf16 (hm, i, d), aliases xb
  // total footprint: 152567808 B (same as round 1)

  cast_all<<<17152, THREADS, 0, stream>>>(x, wq, wk, wv, aK, aV,
                                          xb, wqb, wkb, wvb, aKb, aVtb);
  proj_k<<<2048, THREADS, 0, stream>>>(xb, wqb, qh);
  proj_k<<<2048, THREADS, 0, stream>>>(xb, wkb, kb);
  proj_k<<<2048, THREADS, 0, stream>>>(xb, wvb, vb);
  e2_k<<<256, THREADS, 0, stream>>>(qh, aKb, e2g);
  attn_k<<<512, THREADS, 0, stream>>>(qh, kb, vb, e2g, z1p);
  beta_k<<<2048, THREADS, 0, stream>>>(e2g, beta);
  z2_k<<<256, THREADS, 0, stream>>>(beta, aVtb, z2b);
  reduce_k<<<512, THREADS, 0, stream>>>(z1p, z2b, out);
}

// Round 3
// 440.329 us; speedup vs baseline: 1.4216x; 1.1933x over previous
//
#include <hip/hip_runtime.h>

#define THREADS 256

typedef unsigned short u16;
typedef __attribute__((ext_vector_type(8))) short bf16x8;
typedef __attribute__((ext_vector_type(4))) float f32x4;

// ---- helpers ----------------------------------------------------------
__device__ __forceinline__ u16 f2bf(float f) {
  unsigned int u = __float_as_uint(f);
  u += 0x7fffu + ((u >> 16) & 1u);   // RNE
  return (u16)(u >> 16);
}
__device__ __forceinline__ float bf2f(u16 s) {
  return __uint_as_float(((unsigned int)s) << 16);
}
__device__ __forceinline__ bf16x8 ld8g(const u16* p) {
  return *reinterpret_cast<const bf16x8*>(p);
}
__device__ __forceinline__ bf16x8 ld8s(const u16* p) {
  return *reinterpret_cast<const bf16x8*>(p);
}
__device__ __forceinline__ void st4bf(u16* dst, float4 v) {
  unsigned int lo = (unsigned int)f2bf(v.x) | ((unsigned int)f2bf(v.y) << 16);
  unsigned int hi = (unsigned int)f2bf(v.z) | ((unsigned int)f2bf(v.w) << 16);
  uint2 u; u.x = lo; u.y = hi;
  *reinterpret_cast<uint2*>(dst) = u;
}
__device__ __forceinline__ uint4 pack8(float4 a, float4 b) {
  uint4 r;
  r.x = (unsigned int)f2bf(a.x) | ((unsigned int)f2bf(a.y) << 16);
  r.y = (unsigned int)f2bf(a.z) | ((unsigned int)f2bf(a.w) << 16);
  r.z = (unsigned int)f2bf(b.x) | ((unsigned int)f2bf(b.y) << 16);
  r.w = (unsigned int)f2bf(b.z) | ((unsigned int)f2bf(b.w) << 16);
  return r;
}

// ---- phase 0: cast x + W's to bf16 ------------------------------------
// float4 segments: x 2097152 | Wq 65536 | Wk 65536 | Wv 65536  (total 2293760)
__global__ __launch_bounds__(THREADS) void cast_xw(
    const float* __restrict__ x, const float* __restrict__ wq,
    const float* __restrict__ wk, const float* __restrict__ wv,
    u16* __restrict__ xb, u16* __restrict__ wqb, u16* __restrict__ wkb,
    u16* __restrict__ wvb) {
  int t = blockIdx.x * THREADS + threadIdx.x;
  if (t < 2097152) {
    st4bf(xb + t * 4, reinterpret_cast<const float4*>(x)[t]);
  } else if (t < 2162688) {
    int q = t - 2097152;
    st4bf(wqb + q * 4, reinterpret_cast<const float4*>(wq)[q]);
  } else if (t < 2228224) {
    int q = t - 2162688;
    st4bf(wkb + q * 4, reinterpret_cast<const float4*>(wk)[q]);
  } else if (t < 2293760) {
    int q = t - 2228224;
    st4bf(wvb + q * 4, reinterpret_cast<const float4*>(wv)[q]);
  }
}

// ---- phase 1: fused Q/K/V projection ----------------------------------
// Q -> (hm, i, d)   K -> (hm, j, d)   V -> (hm, d, j)   all bf16, coalesced
__global__ __launch_bounds__(THREADS) void proj3(
    const u16* __restrict__ xb, const u16* __restrict__ wqb,
    const u16* __restrict__ wkb, const u16* __restrict__ wvb,
    u16* __restrict__ qh, u16* __restrict__ kb, u16* __restrict__ vt) {
  const int bm = blockIdx.x >> 3, bn = blockIdx.x & 7;
  const int tid = threadIdx.x;
  const int wave = tid >> 6, lane = tid & 63;
  const int quad = lane >> 4, l15 = lane & 15;
  __shared__ u16 T[64 * 72];
  f32x4 acc[3][4];
#pragma unroll
  for (int w3 = 0; w3 < 3; ++w3)
#pragma unroll
    for (int nt = 0; nt < 4; ++nt) acc[w3][nt] = (f32x4){0.f, 0.f, 0.f, 0.f};
  const u16* arow = xb + (bm * 64 + wave * 16 + l15) * 512 + quad * 8;
  const u16* wptr[3] = {wqb, wkb, wvb};
#pragma unroll 4
  for (int k0 = 0; k0 < 16; ++k0) {
    bf16x8 a = ld8g(arow + k0 * 32);
#pragma unroll
    for (int w3 = 0; w3 < 3; ++w3) {
#pragma unroll
      for (int nt = 0; nt < 4; ++nt) {
        bf16x8 b = ld8g(wptr[w3] + (bn * 64 + nt * 16 + l15) * 512 + k0 * 32 + quad * 8);
        acc[w3][nt] = __builtin_amdgcn_mfma_f32_16x16x32_bf16(a, b, acc[w3][nt], 0, 0, 0);
      }
    }
  }
  const int m = bm >> 2, lpart = (bm & 3) * 64;
  const int hm = bn * 64 + m;
  const int il = tid >> 2, cc = (tid & 3) * 16;
  // --- Q ---
#pragma unroll
  for (int nt = 0; nt < 4; ++nt)
#pragma unroll
    for (int r = 0; r < 4; ++r)
      T[(wave * 16 + quad * 4 + r) * 72 + nt * 16 + l15] = f2bf(acc[0][nt][r]);
  __syncthreads();
  {
    uint4 v0 = *reinterpret_cast<uint4*>(&T[il * 72 + cc]);
    uint4 v1 = *reinterpret_cast<uint4*>(&T[il * 72 + cc + 8]);
    u16* dst = qh + (hm * 256 + lpart + il) * 64 + cc;
    *reinterpret_cast<uint4*>(dst) = v0;
    *reinterpret_cast<uint4*>(dst + 8) = v1;
  }
  __syncthreads();
  // --- K ---
#pragma unroll
  for (int nt = 0; nt < 4; ++nt)
#pragma unroll
    for (int r = 0; r < 4; ++r)
      T[(wave * 16 + quad * 4 + r) * 72 + nt * 16 + l15] = f2bf(acc[1][nt][r]);
  __syncthreads();
  {
    uint4 v0 = *reinterpret_cast<uint4*>(&T[il * 72 + cc]);
    uint4 v1 = *reinterpret_cast<uint4*>(&T[il * 72 + cc + 8]);
    u16* dst = kb + (hm * 256 + lpart + il) * 64 + cc;
    *reinterpret_cast<uint4*>(dst) = v0;
    *reinterpret_cast<uint4*>(dst + 8) = v1;
  }
  __syncthreads();
  // --- V (transposed in LDS: T[d][i_local]) ---
#pragma unroll
  for (int nt = 0; nt < 4; ++nt)
#pragma unroll
    for (int r = 0; r < 4; ++r)
      T[(nt * 16 + l15) * 72 + wave * 16 + quad * 4 + r] = f2bf(acc[2][nt][r]);
  __syncthreads();
  {
    uint4 v0 = *reinterpret_cast<uint4*>(&T[il * 72 + cc]);   // il = d row
    uint4 v1 = *reinterpret_cast<uint4*>(&T[il * 72 + cc + 8]);
    u16* dst = vt + hm * 16384 + il * 256 + lpart + cc;
    *reinterpret_cast<uint4*>(dst) = v0;
    *reinterpret_cast<uint4*>(dst + 8) = v1;
  }
}

// ---- phase 2: e2[hm][i][j] = sum_d q[hm][i][d] * aK[i][j][d] ----------
// grid 2048: i = b>>3, hmt = b&7. aK fp32 read+cast in-kernel to LDS.
__global__ __launch_bounds__(THREADS) void e2_k(
    const u16* __restrict__ qh, const float* __restrict__ aK,
    u16* __restrict__ e2g) {
  const int i = blockIdx.x >> 3, hmt = blockIdx.x & 7;
  const int tid = threadIdx.x;
  const int wave = tid >> 6, lane = tid & 63;
  const int quad = lane >> 4, l15 = lane & 15;
  __shared__ u16 aKl[256 * 72];   // (j, d) bf16, padded; reused as store stage
#pragma unroll
  for (int c = 0; c < 8; ++c) {
    int fidx = c * 2048 + tid * 8;
    int j = fidx >> 6, d = fidx & 63;
    float4 f0 = *reinterpret_cast<const float4*>(aK + i * 16384 + fidx);
    float4 f1 = *reinterpret_cast<const float4*>(aK + i * 16384 + fidx + 4);
    *reinterpret_cast<uint4*>(&aKl[j * 72 + d]) = pack8(f0, f1);
  }
  __syncthreads();
  f32x4 acc[16];
#pragma unroll
  for (int nt = 0; nt < 16; ++nt) acc[nt] = (f32x4){0.f, 0.f, 0.f, 0.f};
  bf16x8 a[2];
#pragma unroll
  for (int ks = 0; ks < 2; ++ks)
    a[ks] = ld8g(qh + ((hmt * 64 + wave * 16 + l15) * 256 + i) * 64 + ks * 32 + quad * 8);
#pragma unroll
  for (int nt = 0; nt < 16; ++nt) {
#pragma unroll
    for (int ks = 0; ks < 2; ++ks) {
      bf16x8 b = ld8s(&aKl[(nt * 16 + l15) * 72 + ks * 32 + quad * 8]);
      acc[nt] = __builtin_amdgcn_mfma_f32_16x16x32_bf16(a[ks], b, acc[nt], 0, 0, 0);
    }
  }
  __syncthreads();                 // all MFMA LDS reads done; reuse aKl
  u16* S = aKl;                    // 64 rows (hm-local) x 264
#pragma unroll
  for (int nt = 0; nt < 16; ++nt)
#pragma unroll
    for (int r = 0; r < 4; ++r)
      S[(wave * 16 + quad * 4 + r) * 264 + nt * 16 + l15] = f2bf(acc[nt][r]);
  __syncthreads();
#pragma unroll
  for (int c = 0; c < 8; ++c) {
    int lin = c * 2048 + tid * 8;
    int row = lin >> 8, col = lin & 255;
    uint4 v = *reinterpret_cast<uint4*>(&S[row * 264 + col]);
    *reinterpret_cast<uint4*>(e2g + ((size_t)(hmt * 64 + row) * 256 + i) * 256 + col) = v;
  }
}

// ---- phase 3: fused scores+softmax+z1, one (hm, i-tile) per block -----
// alpha overwrites e2g; z1p[hm][i][d] bf16 partials. All I/O vectorized.
__global__ __launch_bounds__(THREADS) void attn_k(
    const u16* __restrict__ qh, const u16* __restrict__ kb,
    const u16* __restrict__ vt, u16* __restrict__ e2g,
    u16* __restrict__ z1p) {
  const int bi = blockIdx.x;
  const int hm = bi & 511, it = bi >> 9;   // it-major: same-hm blocks share XCD
  const int tid = threadIdx.x;
  const int wave = tid >> 6, lane = tid & 63;
  const int quad = lane >> 4, l15 = lane & 15;
  __shared__ u16 As[4 * 4224];             // per-wave 16 x 264
  u16* W = &As[wave * 4224];
  // e2 -> LDS (coalesced)
#pragma unroll
  for (int c = 0; c < 8; ++c) {
    int lin = c * 512 + lane * 8;
    int row = lin >> 8, col = lin & 255;
    uint4 v = *reinterpret_cast<const uint4*>(
        e2g + ((size_t)hm * 256 + it * 64 + wave * 16 + row) * 256 + col);
    *reinterpret_cast<uint4*>(&W[row * 264 + col]) = v;
  }
  __syncthreads();
  // e1 = Q K^T
  f32x4 acc[16];
#pragma unroll
  for (int nt = 0; nt < 16; ++nt) acc[nt] = (f32x4){0.f, 0.f, 0.f, 0.f};
  bf16x8 a[2];
#pragma unroll
  for (int ks = 0; ks < 2; ++ks)
    a[ks] = ld8g(qh + ((size_t)hm * 256 + it * 64 + wave * 16 + l15) * 64 + ks * 32 + quad * 8);
#pragma unroll
  for (int nt = 0; nt < 16; ++nt) {
#pragma unroll
    for (int ks = 0; ks < 2; ++ks) {
      bf16x8 b = ld8g(kb + ((size_t)hm * 256 + nt * 16 + l15) * 64 + ks * 32 + quad * 8);
      acc[nt] = __builtin_amdgcn_mfma_f32_16x16x32_bf16(a[ks], b, acc[nt], 0, 0, 0);
    }
  }
  // add e2 (from LDS), scale
#pragma unroll
  for (int nt = 0; nt < 16; ++nt) {
#pragma unroll
    for (int r = 0; r < 4; ++r) {
      float e2v = bf2f(W[(quad * 4 + r) * 264 + nt * 16 + l15]);
      acc[nt][r] = (acc[nt][r] + e2v) * 0.125f;
    }
  }
  // softmax over j (16 lanes x 16 nt per row)
#pragma unroll
  for (int r = 0; r < 4; ++r) {
    float mx = -3.0e38f;
#pragma unroll
    for (int nt = 0; nt < 16; ++nt) mx = fmaxf(mx, acc[nt][r]);
    for (int msk = 1; msk < 16; msk <<= 1) mx = fmaxf(mx, __shfl_xor(mx, msk));
    float s = 0.f;
#pragma unroll
    for (int nt = 0; nt < 16; ++nt) {
      float p = expf(acc[nt][r] - mx);
      acc[nt][r] = p;
      s += p;
    }
    for (int msk = 1; msk < 16; msk <<= 1) s += __shfl_xor(s, msk);
    float inv = 1.0f / s;
    int lrow = quad * 4 + r;
#pragma unroll
    for (int nt = 0; nt < 16; ++nt)
      W[lrow * 264 + nt * 16 + l15] = f2bf(acc[nt][r] * inv);
  }
  __syncthreads();
  // alpha -> global (coalesced, for beta_k)
#pragma unroll
  for (int c = 0; c < 8; ++c) {
    int lin = c * 512 + lane * 8;
    int row = lin >> 8, col = lin & 255;
    uint4 v = *reinterpret_cast<uint4*>(&W[row * 264 + col]);
    *reinterpret_cast<uint4*>(
        e2g + ((size_t)hm * 256 + it * 64 + wave * 16 + row) * 256 + col) = v;
  }
  // z1 = alpha @ V  (B-frags from pre-transposed vt in global/L2)
  f32x4 acc2[4];
#pragma unroll
  for (int nt = 0; nt < 4; ++nt) acc2[nt] = (f32x4){0.f, 0.f, 0.f, 0.f};
#pragma unroll
  for (int ks = 0; ks < 8; ++ks) {
    bf16x8 a2 = ld8s(&W[l15 * 264 + ks * 32 + quad * 8]);
#pragma unroll
    for (int nt = 0; nt < 4; ++nt) {
      bf16x8 b2 = ld8g(vt + (size_t)hm * 16384 + (nt * 16 + l15) * 256 + ks * 32 + quad * 8);
      acc2[nt] = __builtin_amdgcn_mfma_f32_16x16x32_bf16(a2, b2, acc2[nt], 0, 0, 0);
    }
  }
  __syncthreads();
  // z1 tile -> LDS -> coalesced store
#pragma unroll
  for (int nt = 0; nt < 4; ++nt)
#pragma unroll
    for (int r = 0; r < 4; ++r)
      W[(quad * 4 + r) * 264 + nt * 16 + l15] = f2bf(acc2[nt][r]);
  __syncthreads();
  {
    int row = lane >> 2, col = (lane & 3) * 16;
    uint4 v0 = *reinterpret_cast<uint4*>(&W[row * 264 + col]);
    uint4 v1 = *reinterpret_cast<uint4*>(&W[row * 264 + col + 8]);
    u16* dst = z1p + (size_t)hm * 16384 + (it * 64 + wave * 16 + row) * 64 + col;
    *reinterpret_cast<uint4*>(dst) = v0;
    *reinterpret_cast<uint4*>(dst + 8) = v1;
  }
}

// ---- phase 4: beta[h][i][j] = sum_m alpha[(h,m)][i][j] ----------------
__global__ __launch_bounds__(THREADS) void beta_k(
    const u16* __restrict__ alphag, float* __restrict__ beta) {
  const int b = blockIdx.x;
  const int h = b >> 8, i = b & 255;
  const int j = threadIdx.x;
  float s = 0.f;
  const u16* base = alphag + (size_t)(h * 64) * 65536 + i * 256 + j;
#pragma unroll 4
  for (int m = 0; m < 64; ++m) s += bf2f(base[(size_t)m * 65536]);
  beta[(h * 256 + i) * 256 + j] = s;
}

// ---- phase 5: z2b[i][h][d] = beta[h][i][:] @ aV[i] --------------------
// grid 256 (i). aV fp32 transposed in LDS in-kernel.
__global__ __launch_bounds__(THREADS) void z2_k(
    const float* __restrict__ beta, const float* __restrict__ aV,
    float* __restrict__ z2b) {
  const int i = blockIdx.x;
  const int tid = threadIdx.x;
  const int wave = tid >> 6, lane = tid & 63;
  const int quad = lane >> 4, l15 = lane & 15;
  __shared__ u16 aVl[64 * 264];   // (d, j) bf16
#pragma unroll
  for (int c = 0; c < 8; ++c) {
    int fidx = c * 2048 + tid * 8;
    int j = fidx >> 6, d = fidx & 63;
    float4 f0 = *reinterpret_cast<const float4*>(aV + (size_t)i * 16384 + fidx);
    float4 f1 = *reinterpret_cast<const float4*>(aV + (size_t)i * 16384 + fidx + 4);
    float fv[8] = {f0.x, f0.y, f0.z, f0.w, f1.x, f1.y, f1.z, f1.w};
#pragma unroll
    for (int u = 0; u < 8; ++u) aVl[(d + u) * 264 + j] = f2bf(fv[u]);
  }
  __syncthreads();
  f32x4 acc = (f32x4){0.f, 0.f, 0.f, 0.f};
#pragma unroll
  for (int ks = 0; ks < 8; ++ks) {
    u16 ab[8];
    if (l15 < 8) {
      const float* bp = beta + (l15 * 256 + i) * 256 + ks * 32 + quad * 8;
      float4 f0 = *reinterpret_cast<const float4*>(bp);
      float4 f1 = *reinterpret_cast<const float4*>(bp + 4);
      ab[0] = f2bf(f0.x); ab[1] = f2bf(f0.y); ab[2] = f2bf(f0.z); ab[3] = f2bf(f0.w);
      ab[4] = f2bf(f1.x); ab[5] = f2bf(f1.y); ab[6] = f2bf(f1.z); ab[7] = f2bf(f1.w);
    } else {
#pragma unroll
      for (int u = 0; u < 8; ++u) ab[u] = 0;
    }
    bf16x8 a = *reinterpret_cast<bf16x8*>(ab);
    bf16x8 b = ld8s(&aVl[(wave * 16 + l15) * 264 + ks * 32 + quad * 8]);
    acc = __builtin_amdgcn_mfma_f32_16x16x32_bf16(a, b, acc, 0, 0, 0);
  }
#pragma unroll
  for (int r = 0; r < 4; ++r) {
    int h = quad * 4 + r;
    if (h < 8) z2b[i * 512 + h * 64 + wave * 16 + l15] = acc[r];
  }
}

// ---- phase 6: out[i][e] = z2b[i][e] + sum_m z1p[(h,m)][i][d] ----------
__global__ __launch_bounds__(THREADS) void reduce_k(
    const u16* __restrict__ z1p, const float* __restrict__ z2b,
    float* __restrict__ out) {
  int o = blockIdx.x * THREADS + threadIdx.x;   // 131072 total
  int i = o >> 9, e = o & 511;
  int h = e >> 6, d = e & 63;
  float s = z2b[o];
  const u16* base = z1p + (size_t)(h * 64) * 16384 + i * 64 + d;
#pragma unroll 4
  for (int m = 0; m < 64; ++m) s += bf2f(base[(size_t)m * 16384]);
  out[o] = s;
}

// ---- launch -----------------------------------------------------------
extern "C" void kernel_launch(void* const* d_in, const int* in_sizes, int n_in,
                              void* d_out, int out_size, void* d_ws, size_t ws_size,
                              hipStream_t stream) {
  const float* x  = (const float*)d_in[0];
  const float* wq = (const float*)d_in[1];
  const float* wk = (const float*)d_in[2];
  const float* wv = (const float*)d_in[3];
  const float* aK = (const float*)d_in[4];
  const float* aV = (const float*)d_in[5];
  float* out = (float*)d_out;

  char* ws = (char*)d_ws;
  u16* xb    = (u16*)(ws + 0);          // 16 MB (x bf16; later aliased by z1p)
  u16* wqb   = (u16*)(ws + 16777216);
  u16* wkb   = (u16*)(ws + 17301504);
  u16* wvb   = (u16*)(ws + 17825792);
  float* beta= (float*)(ws + 18350080); // 2 MB
  float* z2b = (float*)(ws + 20447232); // 0.5 MB
  u16* qh    = (u16*)(ws + 35127296);   // 16 MB (hm, i, d)
  u16* kb    = (u16*)(ws + 51904512);   // 16 MB (hm, j, d)
  u16* vt    = (u16*)(ws + 68681728);   // 16 MB (hm, d, j)
  u16* e2g   = (u16*)(ws + 85458944);   // 64 MB: e2 then alpha (hm, i, j)
  u16* z1p   = xb;                      // 16 MB (hm, i, d), aliases xb

  cast_xw<<<8960, THREADS, 0, stream>>>(x, wq, wk, wv, xb, wqb, wkb, wvb);
  proj3<<<2048, THREADS, 0, stream>>>(xb, wqb, wkb, wvb, qh, kb, vt);
  e2_k<<<2048, THREADS, 0, stream>>>(qh, aK, e2g);
  attn_k<<<2048, THREADS, 0, stream>>>(qh, kb, vt, e2g, z1p);
  beta_k<<<2048, THREADS, 0, stream>>>(e2g, beta);
  z2_k<<<256, THREADS, 0, stream>>>(beta, aV, z2b);
  reduce_k<<<512, THREADS, 0, stream>>>(z1p, z2b, out);
}

// Round 4
// 300.270 us; speedup vs baseline: 2.0847x; 1.4664x over previous
//
#include <hip/hip_runtime.h>

#define THREADS 256

typedef unsigned short u16;
typedef __attribute__((ext_vector_type(8))) short bf16x8;
typedef __attribute__((ext_vector_type(4))) float f32x4;

// ---- helpers ----------------------------------------------------------
__device__ __forceinline__ u16 f2bf(float f) {
  unsigned int u = __float_as_uint(f);
  u += 0x7fffu + ((u >> 16) & 1u);   // RNE
  return (u16)(u >> 16);
}
__device__ __forceinline__ float bf2f(u16 s) {
  return __uint_as_float(((unsigned int)s) << 16);
}
__device__ __forceinline__ bf16x8 ld8g(const u16* p) {
  return *reinterpret_cast<const bf16x8*>(p);
}
__device__ __forceinline__ bf16x8 ld8s(const u16* p) {
  return *reinterpret_cast<const bf16x8*>(p);
}
__device__ __forceinline__ void st4bf(u16* dst, float4 v) {
  unsigned int lo = (unsigned int)f2bf(v.x) | ((unsigned int)f2bf(v.y) << 16);
  unsigned int hi = (unsigned int)f2bf(v.z) | ((unsigned int)f2bf(v.w) << 16);
  uint2 u; u.x = lo; u.y = hi;
  *reinterpret_cast<uint2*>(dst) = u;
}
__device__ __forceinline__ uint4 pack8(float4 a, float4 b) {
  uint4 r;
  r.x = (unsigned int)f2bf(a.x) | ((unsigned int)f2bf(a.y) << 16);
  r.y = (unsigned int)f2bf(a.z) | ((unsigned int)f2bf(a.w) << 16);
  r.z = (unsigned int)f2bf(b.x) | ((unsigned int)f2bf(b.y) << 16);
  r.w = (unsigned int)f2bf(b.z) | ((unsigned int)f2bf(b.w) << 16);
  return r;
}
// async global->LDS, 16 B per lane; lds dest = wave-uniform base + lane*16
typedef __attribute__((address_space(1))) const unsigned int g_u32;
typedef __attribute__((address_space(3))) unsigned int l_u32;
__device__ __forceinline__ void async16(const u16* g, u16* l) {
  __builtin_amdgcn_global_load_lds((g_u32*)g, (l_u32*)l, 16, 0, 0);
}

// ---- phase 0: cast x + W's to bf16 ------------------------------------
__global__ __launch_bounds__(THREADS) void cast_xw(
    const float* __restrict__ x, const float* __restrict__ wq,
    const float* __restrict__ wk, const float* __restrict__ wv,
    u16* __restrict__ xb, u16* __restrict__ wqb, u16* __restrict__ wkb,
    u16* __restrict__ wvb) {
  int t = blockIdx.x * THREADS + threadIdx.x;
  if (t < 2097152) {
    st4bf(xb + t * 4, reinterpret_cast<const float4*>(x)[t]);
  } else if (t < 2162688) {
    int q = t - 2097152;
    st4bf(wqb + q * 4, reinterpret_cast<const float4*>(wq)[q]);
  } else if (t < 2228224) {
    int q = t - 2162688;
    st4bf(wkb + q * 4, reinterpret_cast<const float4*>(wk)[q]);
  } else if (t < 2293760) {
    int q = t - 2228224;
    st4bf(wvb + q * 4, reinterpret_cast<const float4*>(wv)[q]);
  }
}

// ---- phase 1: Q/K/V projection as one 16384x1536x512 GEMM -------------
// m97-style: 128x128 tile, BK=32, global_load_lds staging, swizzled LDS.
// Epilogue permutes: Q->(hm,i,d)  K->(hm,j,d)  V->(hm,d,j), coalesced.
__global__ __launch_bounds__(THREADS) void proj_gemm(
    const u16* __restrict__ xb, const u16* __restrict__ wb,
    u16* __restrict__ qh, u16* __restrict__ kb, u16* __restrict__ vt) {
  const int bm = blockIdx.x / 12, bn = blockIdx.x % 12;
  const int tid = threadIdx.x;
  const int wave = tid >> 6, lane = tid & 63;
  const int quad = lane >> 4, l15 = lane & 15;
  __shared__ __align__(16) u16 smem[9216];   // 18432 B: staging + epilogue
  u16* At = smem;                            // 128 rows x 32 k (swizzled), 4096 u16
  u16* Bt = smem + 4096;                     // 128 rows x 32 k (swizzled)

  // staging geometry (constant per lane)
  const int rowL = lane >> 2;                          // 0..15
  const int chunkL = (lane & 3) ^ ((lane >> 3) & 3);   // swizzled k-chunk
  const u16* gA = xb + (size_t)(bm * 128 + wave * 32 + rowL) * 512 + chunkL * 8;
  const u16* gB = wb + (size_t)(bn * 128 + wave * 32 + rowL) * 512 + chunkL * 8;
  u16* lA = At + wave * 1024;   // + inst*512, + lane*8 by HW
  u16* lB = Bt + wave * 1024;

  const int rw0 = (wave & 1) * 64, cw0 = (wave >> 1) * 64;
  const int swz = (quad ^ ((l15 >> 1) & 3)) * 8;

  f32x4 acc[4][4];
#pragma unroll
  for (int mt = 0; mt < 4; ++mt)
#pragma unroll
    for (int nt = 0; nt < 4; ++nt) acc[mt][nt] = (f32x4){0.f, 0.f, 0.f, 0.f};

  for (int s = 0; s < 16; ++s) {
    __syncthreads();                    // prev tile's readers done
    async16(gA + s * 32, lA);
    async16(gA + s * 32 + 8192, lA + 512);   // +16 rows
    async16(gB + s * 32, lB);
    async16(gB + s * 32 + 8192, lB + 512);
    __syncthreads();                    // stage complete (vmcnt drained)
    bf16x8 af[4], bf[4];
#pragma unroll
    for (int mt = 0; mt < 4; ++mt)
      af[mt] = ld8s(At + (rw0 + mt * 16 + l15) * 32 + swz);
#pragma unroll
    for (int nt = 0; nt < 4; ++nt)
      bf[nt] = ld8s(Bt + (cw0 + nt * 16 + l15) * 32 + swz);
#pragma unroll
    for (int mt = 0; mt < 4; ++mt)
#pragma unroll
      for (int nt = 0; nt < 4; ++nt)
        acc[mt][nt] = __builtin_amdgcn_mfma_f32_16x16x32_bf16(af[mt], bf[nt], acc[mt][nt], 0, 0, 0);
  }

  // ---- epilogue ----
  const int mat = bn >> 2;              // 0=Q 1=K 2=V
  const int h0 = (bn & 3) * 2;          // two heads per tile
  const int m = bm >> 1;
  const int l0 = (bm & 1) * 128;

  if (mat < 2) {
    u16* dstb = (mat == 0) ? qh : kb;
    const int il = tid >> 1, cc = (tid & 1) * 32;
#pragma unroll
    for (int p = 0; p < 2; ++p) {       // one h (64 cols) per pass
      __syncthreads();
      if ((wave >> 1) == p) {           // this wave-pair owns these cols
#pragma unroll
        for (int mt = 0; mt < 4; ++mt)
#pragma unroll
          for (int nt = 0; nt < 4; ++nt)
#pragma unroll
            for (int r = 0; r < 4; ++r)
              smem[(rw0 + mt * 16 + quad * 4 + r) * 72 + nt * 16 + l15] =
                  f2bf(acc[mt][nt][r]);
      }
      __syncthreads();
      u16* dst = dstb + ((size_t)((h0 + p) * 64 + m) * 256 + l0 + il) * 64 + cc;
      uint4 v0 = *reinterpret_cast<uint4*>(&smem[il * 72 + cc]);
      uint4 v1 = *reinterpret_cast<uint4*>(&smem[il * 72 + cc + 8]);
      uint4 v2 = *reinterpret_cast<uint4*>(&smem[il * 72 + cc + 16]);
      uint4 v3 = *reinterpret_cast<uint4*>(&smem[il * 72 + cc + 24]);
      *reinterpret_cast<uint4*>(dst) = v0;
      *reinterpret_cast<uint4*>(dst + 8) = v1;
      *reinterpret_cast<uint4*>(dst + 16) = v2;
      *reinterpret_cast<uint4*>(dst + 24) = v3;
    }
  } else {
    const int tl = tid >> 2, cc = (tid & 3) * 32;
#pragma unroll
    for (int p = 0; p < 2; ++p) {
      __syncthreads();
      if ((wave >> 1) == p) {           // transpose: T[dh][l], stride 136
#pragma unroll
        for (int mt = 0; mt < 4; ++mt)
#pragma unroll
          for (int nt = 0; nt < 4; ++nt)
#pragma unroll
            for (int r = 0; r < 4; ++r)
              smem[(nt * 16 + l15) * 136 + rw0 + mt * 16 + quad * 4 + r] =
                  f2bf(acc[mt][nt][r]);
      }
      __syncthreads();
      int hm = (h0 + p) * 64 + m;
      u16* dst = vt + (size_t)hm * 16384 + tl * 256 + l0 + cc;
      uint4 v0 = *reinterpret_cast<uint4*>(&smem[tl * 136 + cc]);
      uint4 v1 = *reinterpret_cast<uint4*>(&smem[tl * 136 + cc + 8]);
      uint4 v2 = *reinterpret_cast<uint4*>(&smem[tl * 136 + cc + 16]);
      uint4 v3 = *reinterpret_cast<uint4*>(&smem[tl * 136 + cc + 24]);
      *reinterpret_cast<uint4*>(dst) = v0;
      *reinterpret_cast<uint4*>(dst + 8) = v1;
      *reinterpret_cast<uint4*>(dst + 16) = v2;
      *reinterpret_cast<uint4*>(dst + 24) = v3;
    }
  }
}

// ---- phase 2: e2[hm][i][j] = sum_d q[hm][i][d] * aK[i][j][d] ----------
__global__ __launch_bounds__(THREADS) void e2_k(
    const u16* __restrict__ qh, const float* __restrict__ aK,
    u16* __restrict__ e2g) {
  const int i = blockIdx.x >> 3, hmt = blockIdx.x & 7;
  const int tid = threadIdx.x;
  const int wave = tid >> 6, lane = tid & 63;
  const int quad = lane >> 4, l15 = lane & 15;
  __shared__ u16 aKl[256 * 72];   // (j, d) bf16, padded; reused as store stage
#pragma unroll
  for (int c = 0; c < 8; ++c) {
    int fidx = c * 2048 + tid * 8;
    int j = fidx >> 6, d = fidx & 63;
    float4 f0 = *reinterpret_cast<const float4*>(aK + i * 16384 + fidx);
    float4 f1 = *reinterpret_cast<const float4*>(aK + i * 16384 + fidx + 4);
    *reinterpret_cast<uint4*>(&aKl[j * 72 + d]) = pack8(f0, f1);
  }
  __syncthreads();
  f32x4 acc[16];
#pragma unroll
  for (int nt = 0; nt < 16; ++nt) acc[nt] = (f32x4){0.f, 0.f, 0.f, 0.f};
  bf16x8 a[2];
#pragma unroll
  for (int ks = 0; ks < 2; ++ks)
    a[ks] = ld8g(qh + ((hmt * 64 + wave * 16 + l15) * 256 + i) * 64 + ks * 32 + quad * 8);
#pragma unroll
  for (int nt = 0; nt < 16; ++nt) {
#pragma unroll
    for (int ks = 0; ks < 2; ++ks) {
      bf16x8 b = ld8s(&aKl[(nt * 16 + l15) * 72 + ks * 32 + quad * 8]);
      acc[nt] = __builtin_amdgcn_mfma_f32_16x16x32_bf16(a[ks], b, acc[nt], 0, 0, 0);
    }
  }
  __syncthreads();                 // all MFMA LDS reads done; reuse aKl
  u16* S = aKl;                    // 64 rows (hm-local) x 264
#pragma unroll
  for (int nt = 0; nt < 16; ++nt)
#pragma unroll
    for (int r = 0; r < 4; ++r)
      S[(wave * 16 + quad * 4 + r) * 264 + nt * 16 + l15] = f2bf(acc[nt][r]);
  __syncthreads();
#pragma unroll
  for (int c = 0; c < 8; ++c) {
    int lin = c * 2048 + tid * 8;
    int row = lin >> 8, col = lin & 255;
    uint4 v = *reinterpret_cast<uint4*>(&S[row * 264 + col]);
    *reinterpret_cast<uint4*>(e2g + ((size_t)(hmt * 64 + row) * 256 + i) * 256 + col) = v;
  }
}

// ---- phase 3: fused scores+softmax+z1, one (hm, i-tile) per block -----
__global__ __launch_bounds__(THREADS) void attn_k(
    const u16* __restrict__ qh, const u16* __restrict__ kb,
    const u16* __restrict__ vt, u16* __restrict__ e2g,
    u16* __restrict__ z1p) {
  const int bi = blockIdx.x;
  const int hm = bi & 511, it = bi >> 9;   // it-major: same-hm blocks share XCD
  const int tid = threadIdx.x;
  const int wave = tid >> 6, lane = tid & 63;
  const int quad = lane >> 4, l15 = lane & 15;
  __shared__ u16 As[4 * 4224];             // per-wave 16 x 264
  u16* W = &As[wave * 4224];
  // e2 -> LDS (coalesced)
#pragma unroll
  for (int c = 0; c < 8; ++c) {
    int lin = c * 512 + lane * 8;
    int row = lin >> 8, col = lin & 255;
    uint4 v = *reinterpret_cast<const uint4*>(
        e2g + ((size_t)hm * 256 + it * 64 + wave * 16 + row) * 256 + col);
    *reinterpret_cast<uint4*>(&W[row * 264 + col]) = v;
  }
  __syncthreads();
  // e1 = Q K^T
  f32x4 acc[16];
#pragma unroll
  for (int nt = 0; nt < 16; ++nt) acc[nt] = (f32x4){0.f, 0.f, 0.f, 0.f};
  bf16x8 a[2];
#pragma unroll
  for (int ks = 0; ks < 2; ++ks)
    a[ks] = ld8g(qh + ((size_t)hm * 256 + it * 64 + wave * 16 + l15) * 64 + ks * 32 + quad * 8);
#pragma unroll
  for (int nt = 0; nt < 16; ++nt) {
#pragma unroll
    for (int ks = 0; ks < 2; ++ks) {
      bf16x8 b = ld8g(kb + ((size_t)hm * 256 + nt * 16 + l15) * 64 + ks * 32 + quad * 8);
      acc[nt] = __builtin_amdgcn_mfma_f32_16x16x32_bf16(a[ks], b, acc[nt], 0, 0, 0);
    }
  }
  // add e2 (from LDS), scale
#pragma unroll
  for (int nt = 0; nt < 16; ++nt) {
#pragma unroll
    for (int r = 0; r < 4; ++r) {
      float e2v = bf2f(W[(quad * 4 + r) * 264 + nt * 16 + l15]);
      acc[nt][r] = (acc[nt][r] + e2v) * 0.125f;
    }
  }
  // softmax over j (16 lanes x 16 nt per row)
#pragma unroll
  for (int r = 0; r < 4; ++r) {
    float mx = -3.0e38f;
#pragma unroll
    for (int nt = 0; nt < 16; ++nt) mx = fmaxf(mx, acc[nt][r]);
    for (int msk = 1; msk < 16; msk <<= 1) mx = fmaxf(mx, __shfl_xor(mx, msk));
    float s = 0.f;
#pragma unroll
    for (int nt = 0; nt < 16; ++nt) {
      float p = expf(acc[nt][r] - mx);
      acc[nt][r] = p;
      s += p;
    }
    for (int msk = 1; msk < 16; msk <<= 1) s += __shfl_xor(s, msk);
    float inv = 1.0f / s;
    int lrow = quad * 4 + r;
#pragma unroll
    for (int nt = 0; nt < 16; ++nt)
      W[lrow * 264 + nt * 16 + l15] = f2bf(acc[nt][r] * inv);
  }
  __syncthreads();
  // alpha -> global (coalesced, for beta_k)
#pragma unroll
  for (int c = 0; c < 8; ++c) {
    int lin = c * 512 + lane * 8;
    int row = lin >> 8, col = lin & 255;
    uint4 v = *reinterpret_cast<uint4*>(&W[row * 264 + col]);
    *reinterpret_cast<uint4*>(
        e2g + ((size_t)hm * 256 + it * 64 + wave * 16 + row) * 256 + col) = v;
  }
  // z1 = alpha @ V  (B-frags from pre-transposed vt in global/L2)
  f32x4 acc2[4];
#pragma unroll
  for (int nt = 0; nt < 4; ++nt) acc2[nt] = (f32x4){0.f, 0.f, 0.f, 0.f};
#pragma unroll
  for (int ks = 0; ks < 8; ++ks) {
    bf16x8 a2 = ld8s(&W[l15 * 264 + ks * 32 + quad * 8]);
#pragma unroll
    for (int nt = 0; nt < 4; ++nt) {
      bf16x8 b2 = ld8g(vt + (size_t)hm * 16384 + (nt * 16 + l15) * 256 + ks * 32 + quad * 8);
      acc2[nt] = __builtin_amdgcn_mfma_f32_16x16x32_bf16(a2, b2, acc2[nt], 0, 0, 0);
    }
  }
  __syncthreads();
  // z1 tile -> LDS -> coalesced store
#pragma unroll
  for (int nt = 0; nt < 4; ++nt)
#pragma unroll
    for (int r = 0; r < 4; ++r)
      W[(quad * 4 + r) * 264 + nt * 16 + l15] = f2bf(acc2[nt][r]);
  __syncthreads();
  {
    int row = lane >> 2, col = (lane & 3) * 16;
    uint4 v0 = *reinterpret_cast<uint4*>(&W[row * 264 + col]);
    uint4 v1 = *reinterpret_cast<uint4*>(&W[row * 264 + col + 8]);
    u16* dst = z1p + (size_t)hm * 16384 + (it * 64 + wave * 16 + row) * 64 + col;
    *reinterpret_cast<uint4*>(dst) = v0;
    *reinterpret_cast<uint4*>(dst + 8) = v1;
  }
}

// ---- phase 4: beta[h][i][j] = sum_m alpha[(h,m)][i][j] ----------------
__global__ __launch_bounds__(THREADS) void beta_k(
    const u16* __restrict__ alphag, float* __restrict__ beta) {
  const int b = blockIdx.x;
  const int h = b >> 8, i = b & 255;
  const int j = threadIdx.x;
  float s = 0.f;
  const u16* base = alphag + (size_t)(h * 64) * 65536 + i * 256 + j;
#pragma unroll 4
  for (int m = 0; m < 64; ++m) s += bf2f(base[(size_t)m * 65536]);
  beta[(h * 256 + i) * 256 + j] = s;
}

// ---- phase 5: z2b[i][h][d] = beta[h][i][:] @ aV[i] --------------------
__global__ __launch_bounds__(THREADS) void z2_k(
    const float* __restrict__ beta, const float* __restrict__ aV,
    float* __restrict__ z2b) {
  const int i = blockIdx.x;
  const int tid = threadIdx.x;
  const int wave = tid >> 6, lane = tid & 63;
  const int quad = lane >> 4, l15 = lane & 15;
  __shared__ u16 aVl[64 * 264];   // (d, j) bf16
#pragma unroll
  for (int c = 0; c < 8; ++c) {
    int fidx = c * 2048 + tid * 8;
    int j = fidx >> 6, d = fidx & 63;
    float4 f0 = *reinterpret_cast<const float4*>(aV + (size_t)i * 16384 + fidx);
    float4 f1 = *reinterpret_cast<const float4*>(aV + (size_t)i * 16384 + fidx + 4);
    float fv[8] = {f0.x, f0.y, f0.z, f0.w, f1.x, f1.y, f1.z, f1.w};
#pragma unroll
    for (int u = 0; u < 8; ++u) aVl[(d + u) * 264 + j] = f2bf(fv[u]);
  }
  __syncthreads();
  f32x4 acc = (f32x4){0.f, 0.f, 0.f, 0.f};
#pragma unroll
  for (int ks = 0; ks < 8; ++ks) {
    u16 ab[8];
    if (l15 < 8) {
      const float* bp = beta + (l15 * 256 + i) * 256 + ks * 32 + quad * 8;
      float4 f0 = *reinterpret_cast<const float4*>(bp);
      float4 f1 = *reinterpret_cast<const float4*>(bp + 4);
      ab[0] = f2bf(f0.x); ab[1] = f2bf(f0.y); ab[2] = f2bf(f0.z); ab[3] = f2bf(f0.w);
      ab[4] = f2bf(f1.x); ab[5] = f2bf(f1.y); ab[6] = f2bf(f1.z); ab[7] = f2bf(f1.w);
    } else {
#pragma unroll
      for (int u = 0; u < 8; ++u) ab[u] = 0;
    }
    bf16x8 a = *reinterpret_cast<bf16x8*>(ab);
    bf16x8 b = ld8s(&aVl[(wave * 16 + l15) * 264 + ks * 32 + quad * 8]);
    acc = __builtin_amdgcn_mfma_f32_16x16x32_bf16(a, b, acc, 0, 0, 0);
  }
#pragma unroll
  for (int r = 0; r < 4; ++r) {
    int h = quad * 4 + r;
    if (h < 8) z2b[i * 512 + h * 64 + wave * 16 + l15] = acc[r];
  }
}

// ---- phase 6: out[i][e] = z2b[i][e] + sum_m z1p[(h,m)][i][d] ----------
__global__ __launch_bounds__(THREADS) void reduce_k(
    const u16* __restrict__ z1p, const float* __restrict__ z2b,
    float* __restrict__ out) {
  int o = blockIdx.x * THREADS + threadIdx.x;   // 131072 total
  int i = o >> 9, e = o & 511;
  int h = e >> 6, d = e & 63;
  float s = z2b[o];
  const u16* base = z1p + (size_t)(h * 64) * 16384 + i * 64 + d;
#pragma unroll 4
  for (int m = 0; m < 64; ++m) s += bf2f(base[(size_t)m * 16384]);
  out[o] = s;
}

// ---- launch -----------------------------------------------------------
extern "C" void kernel_launch(void* const* d_in, const int* in_sizes, int n_in,
                              void* d_out, int out_size, void* d_ws, size_t ws_size,
                              hipStream_t stream) {
  const float* x  = (const float*)d_in[0];
  const float* wq = (const float*)d_in[1];
  const float* wk = (const float*)d_in[2];
  const float* wv = (const float*)d_in[3];
  const float* aK = (const float*)d_in[4];
  const float* aV = (const float*)d_in[5];
  float* out = (float*)d_out;

  char* ws = (char*)d_ws;
  u16* xb    = (u16*)(ws + 0);          // 16 MB (x bf16; later aliased by z1p)
  u16* wqb   = (u16*)(ws + 16777216);   // Wq/Wk/Wv contiguous = B (1536x512)
  u16* wkb   = (u16*)(ws + 17301504);
  u16* wvb   = (u16*)(ws + 17825792);
  float* beta= (float*)(ws + 18350080); // 2 MB
  float* z2b = (float*)(ws + 20447232); // 0.5 MB
  u16* qh    = (u16*)(ws + 35127296);   // 16 MB (hm, i, d)
  u16* kb    = (u16*)(ws + 51904512);   // 16 MB (hm, j, d)
  u16* vt    = (u16*)(ws + 68681728);   // 16 MB (hm, d, j)
  u16* e2g   = (u16*)(ws + 85458944);   // 64 MB: e2 then alpha (hm, i, j)
  u16* z1p   = xb;                      // 16 MB (hm, i, d), aliases xb

  cast_xw<<<8960, THREADS, 0, stream>>>(x, wq, wk, wv, xb, wqb, wkb, wvb);
  proj_gemm<<<1536, THREADS, 0, stream>>>(xb, wqb, qh, kb, vt);
  e2_k<<<2048, THREADS, 0, stream>>>(qh, aK, e2g);
  attn_k<<<2048, THREADS, 0, stream>>>(qh, kb, vt, e2g, z1p);
  beta_k<<<2048, THREADS, 0, stream>>>(e2g, beta);
  z2_k<<<256, THREADS, 0, stream>>>(beta, aV, z2b);
  reduce_k<<<512, THREADS, 0, stream>>>(z1p, z2b, out);
}